// Round 2
// baseline (1084.133 us; speedup 1.0000x reference)
//
#include <hip/hip_runtime.h>

// VecLeadingZeroDetector108: X [n_rows, 108] float32 bits (exact 0.0/1.0),
// out [n_rows, 7] float32 = binary (MSB-first) index of first set bit, or
// 108 = 1101100b if the row is all zero.
//
// R1 strategy: block-cooperative, fully coalesced. A block of 256 threads owns
// 256 consecutive rows = one contiguous 256*108-float region (108 % 4 == 0, so
// every float4 is within a single row). Threads sweep it with coalesced float4
// loads, OR nonzero-nibbles into per-row 4xu32 LDS bitmasks (atomicOr only when
// nibble != 0, ~11.5% of lanes at p=0.03), then thread t scans row t's mask
// with __ffs and the block writes the 7-bit encodings back via coalesced
// float4 stores from an LDS staging buffer.

#define NBITS 108
#define NOUT 7
#define RPB 256                       // rows per block == blockDim.x
#define F4_PER_ROW 27                 // 108 / 4
#define F4_PER_BLOCK (RPB * F4_PER_ROW)   // 6912

__global__ __launch_bounds__(256) void lzd108_kernel(const float4* __restrict__ X4,
                                                     float* __restrict__ out,
                                                     int n_rows) {
    __shared__ unsigned masks[RPB][4];                 // 108 bits per row, LSB-first within word
    __shared__ __align__(16) float obuf[RPB * NOUT];   // output staging

    const int tid = threadIdx.x;
    const long long block_row0 = (long long)blockIdx.x * RPB;

    masks[tid][0] = 0u;
    masks[tid][1] = 0u;
    masks[tid][2] = 0u;
    masks[tid][3] = 0u;
    __syncthreads();

    int rows_here = n_rows - (int)block_row0;
    if (rows_here > RPB) rows_here = RPB;
    const bool full = (rows_here == RPB);

    const float4* base = X4 + block_row0 * F4_PER_ROW;
    const int total_f4 = rows_here * F4_PER_ROW;

    if (full) {
        #pragma unroll
        for (int i = 0; i < F4_PER_ROW; ++i) {
            const int q = i * RPB + tid;
            float4 v = base[q];
            unsigned m = 0u;
            m |= (v.x != 0.0f) ? 1u : 0u;
            m |= (v.y != 0.0f) ? 2u : 0u;
            m |= (v.z != 0.0f) ? 4u : 0u;
            m |= (v.w != 0.0f) ? 8u : 0u;
            if (m) {
                const int local_row = q / F4_PER_ROW;        // magic-mul, only ~11.5% of lanes
                const int bit0 = (q - local_row * F4_PER_ROW) * 4;
                atomicOr(&masks[local_row][bit0 >> 5], m << (bit0 & 31));
            }
        }
    } else {
        for (int q = tid; q < total_f4; q += RPB) {
            float4 v = base[q];
            unsigned m = 0u;
            m |= (v.x != 0.0f) ? 1u : 0u;
            m |= (v.y != 0.0f) ? 2u : 0u;
            m |= (v.z != 0.0f) ? 4u : 0u;
            m |= (v.w != 0.0f) ? 8u : 0u;
            if (m) {
                const int local_row = q / F4_PER_ROW;
                const int bit0 = (q - local_row * F4_PER_ROW) * 4;
                atomicOr(&masks[local_row][bit0 >> 5], m << (bit0 & 31));
            }
        }
    }
    __syncthreads();

    if (tid < rows_here) {
        const unsigned w0 = masks[tid][0];
        const unsigned w1 = masks[tid][1];
        const unsigned w2 = masks[tid][2];
        const unsigned w3 = masks[tid][3];
        int idx;
        if (w0)      idx =       __ffs(w0) - 1;
        else if (w1) idx = 32  + __ffs(w1) - 1;
        else if (w2) idx = 64  + __ffs(w2) - 1;
        else if (w3) idx = 96  + __ffs(w3) - 1;
        else         idx = NBITS;
        float* o = &obuf[tid * NOUT];
        o[0] = (float)((idx >> 6) & 1);
        o[1] = (float)((idx >> 5) & 1);
        o[2] = (float)((idx >> 4) & 1);
        o[3] = (float)((idx >> 3) & 1);
        o[4] = (float)((idx >> 2) & 1);
        o[5] = (float)((idx >> 1) & 1);
        o[6] = (float)(idx & 1);
    }
    __syncthreads();

    // Coalesced writeback of 256*7 floats (= 448 float4 for full blocks).
    float* gout = out + block_row0 * NOUT;   // byte offset 7168*blockIdx -> 16B aligned
    if (full) {
        float4* g4 = reinterpret_cast<float4*>(gout);
        const float4* s4 = reinterpret_cast<const float4*>(obuf);
        #pragma unroll
        for (int i = 0; i < (RPB * NOUT) / 4 / RPB + 1; ++i) {  // 448/256 -> 2 iters
            const int q = i * RPB + tid;
            if (q < (RPB * NOUT) / 4) g4[q] = s4[q];
        }
    } else {
        const int total_f = rows_here * NOUT;
        for (int q = tid; q < total_f; q += RPB) gout[q] = obuf[q];
    }
}

extern "C" void kernel_launch(void* const* d_in, const int* in_sizes, int n_in,
                              void* d_out, int out_size, void* d_ws, size_t ws_size,
                              hipStream_t stream) {
    const float4* X4 = (const float4*)d_in[0];
    float* out = (float*)d_out;
    const int n_rows = in_sizes[0] / NBITS;
    const int grid = (n_rows + RPB - 1) / RPB;
    lzd108_kernel<<<grid, RPB, 0, stream>>>(X4, out, n_rows);
}